// Round 6
// baseline (197.134 us; speedup 1.0000x reference)
//
#include <hip/hip_runtime.h>
#include <math.h>

#define T_LEN 32000
#define B_N 8
#define O_N 128
#define NTAPS 10
#define TILE_T 1280            // 5 t per thread x 256 threads
#define NT 5
#define PAD 2944               // >= ceil(9 * Dmax), Dmax = 320; PAD % 4 == 0
#define NSTAGE (TILE_T + PAD + 1)        // 4225 floats
#define NSTAGE_AL ((NSTAGE + 3) & ~3)    // 4228 floats = 16.9 KB LDS
#define OCHUNK 16

// ---------------- kernel 1: per-channel tap parameters -> d_ws ----------------
// Replicates the reference rounding chain: f = fl32(50 * 40^sigmoid(f_raw)),
// D = fl32(16000 / f), kD = fl32(k * D). f64 for sigmoid/pow accuracy, one
// final rounding to f32 (correctly rounded, within 1 ulp of XLA's f32 chain).
__global__ __launch_bounds__(128) void comb_params_kernel(
    const float* __restrict__ f, const float* __restrict__ a,
    float* __restrict__ tp) {
  int o = threadIdx.x;  // 128 threads, 1 block
  double fr = (double)f[o];
  double sig = 1.0 / (1.0 + exp(-fr));
  float ff = (float)(50.0 * pow(40.0, sig));  // round to f32
  float D = 16000.0f / ff;                    // f32 divide, correctly rounded
  float av = a[o];
  for (int k = 0; k < NTAPS; ++k) {
    tp[o * 20 + k] = (float)k * D;                           // fl32(k * D)
    tp[o * 20 + 10 + k] = (float)pow((double)av, (double)k); // a^k
  }
}

// ---------------- kernel 2: main comb ----------------
// One DS op (8 B) per tap is the structural floor for this access pattern
// (stride-8B conflict-free; wider shared-window reads induce 8-32-way bank
// conflicts at 16-64B lane strides). This version attacks the staging
// overhead instead: TILE_T=1280 drops staged-bytes/output from 12.5 to 3.3
// and block count 8000 -> 1600, with float4 staging on interior tiles.
template <bool SAFE>
__device__ __forceinline__ void comb_body(const float* __restrict__ tp,
                                          float* __restrict__ outp,
                                          const float* sx, int oc,
                                          const float* tf, int base_g) {
#pragma unroll 1
  for (int oi = 0; oi < OCHUNK; ++oi) {
    const float* __restrict__ p = tp + (oc + oi) * 20;  // uniform -> s_load
    float acc[NT];
#pragma unroll
    for (int j = 0; j < NT; ++j) acc[j] = 0.0f;
    for (int k = 0; k < NTAPS; ++k) {
      float kD = p[k];
      float ak = p[10 + k];
#pragma unroll
      for (int j = 0; j < NT; ++j) {
        float pos = tf[j] - kD;                  // fl(t - kD), exact ref chain
        float frac = __builtin_amdgcn_fractf(pos);  // pos - floor(pos)
        int idx = (int)pos - base_g;             // trunc==floor for pos>=0;
                                                 // neg-pos taps masked below
        float x0 = sx[idx];                      // adjacent -> ds_read2_b32
        float x1 = sx[idx + 1];
        float tap = fmaf(frac, x1 - x0, x0);
        if (!SAFE) tap = (pos >= 0.0f) ? tap : 0.0f;  // valid = floor(pos)>=0
        acc[j] = fmaf(ak, tap, acc[j]);
      }
    }
#pragma unroll
    for (int j = 0; j < NT; ++j)
      outp[(size_t)oi * T_LEN + 256 * j] = acc[j];
  }
}

__global__ __launch_bounds__(256) void comb_main_kernel(
    const float* __restrict__ x, const float* __restrict__ tp,
    float* __restrict__ out) {
  __shared__ float sx[NSTAGE_AL];
  int bx = blockIdx.x;
  int t0 = bx * TILE_T;
  int b = blockIdx.y;
  int oc = blockIdx.z * OCHUNK;
  const float* __restrict__ xrow = x + b * T_LEN;
  int base_g = t0 - PAD;
  int tid = threadIdx.x;

  if (bx >= 3 && bx <= 23) {
    // interior tile: every g in [0, 31999] -> pure float4 copy, no clamps.
    // base_g % 4 == 0 (TILE_T, PAD both multiples of 4) -> aligned.
    float4* s4 = (float4*)sx;
    const float4* g4 = (const float4*)(xrow + base_g);
#pragma unroll 1
    for (int j = tid; j < NSTAGE_AL / 4; j += 256) s4[j] = g4[j];
  } else {
    // edge tiles: g<0 -> 0.0 (reads stay finite; those taps are masked);
    // g >= T-1 -> clamp to T-1 (replicates reference i1 clip, weight 0).
#pragma unroll 1
    for (int j = tid; j < NSTAGE_AL; j += 256) {
      int g = base_g + j;
      float v = 0.0f;
      if (g >= 0) v = xrow[g < T_LEN - 1 ? g : T_LEN - 1];
      sx[j] = v;
    }
  }
  __syncthreads();

  float tf[NT];
#pragma unroll
  for (int j = 0; j < NT; ++j) tf[j] = (float)(t0 + tid + 256 * j);
  float* outp = out + ((size_t)b * O_N + oc) * T_LEN + t0 + tid;

  if (t0 >= PAD)       // pos >= 64 for every tap: no masking needed
    comb_body<true>(tp, outp, sx, oc, tf, base_g);
  else
    comb_body<false>(tp, outp, sx, oc, tf, base_g);
}

// ---------------- launch ----------------
extern "C" void kernel_launch(void* const* d_in, const int* in_sizes, int n_in,
                              void* d_out, int out_size, void* d_ws,
                              size_t ws_size, hipStream_t stream) {
  const float* x = (const float*)d_in[0];  // (8,1,32000) f32
  const float* f = (const float*)d_in[1];  // (128,1) f32
  const float* a = (const float*)d_in[2];  // (128,1) f32
  float* out = (float*)d_out;              // (8,128,32000) f32
  float* tp = (float*)d_ws;                // 128*20 floats = 10 KB scratch

  comb_params_kernel<<<1, 128, 0, stream>>>(f, a, tp);

  dim3 grid(T_LEN / TILE_T, B_N, O_N / OCHUNK);  // (25, 8, 8) = 1600 blocks
  comb_main_kernel<<<grid, 256, 0, stream>>>(x, tp, out);
}

// Round 7
// 173.977 us; speedup vs baseline: 1.1331x; 1.1331x over previous
//
#include <hip/hip_runtime.h>
#include <math.h>

#define T_LEN 32000
#define B_N 8
#define O_N 128
#define NTAPS 10
#define TILE_T 1280            // 5 t per thread x 256 threads
#define NT 5
#define PAD 2944               // >= ceil(9*Dmax)+margin, Dmax = 320; PAD % 4 == 0
#define NSTAGE (TILE_T + PAD + 1)        // 4225 floats
#define NSTAGE_AL ((NSTAGE + 3) & ~3)    // 4228 floats = 16.9 KB LDS
#define OCHUNK 8
#define TC 640                 // tile-center offset

// ---------------- kernel 1: per-channel tap parameters -> d_ws ----------------
// f = fl32(50 * 40^sigmoid(f_raw)), D = fl32(16000/f), kD = fl32(k*D), a^k.
// f64 for sigmoid/pow accuracy, one final rounding to f32.
__global__ __launch_bounds__(128) void comb_params_kernel(
    const float* __restrict__ f, const float* __restrict__ a,
    float* __restrict__ tp) {
  int o = threadIdx.x;  // 128 threads, 1 block
  double fr = (double)f[o];
  double sig = 1.0 / (1.0 + exp(-fr));
  float ff = (float)(50.0 * pow(40.0, sig));
  float D = 16000.0f / ff;
  float av = a[o];
  for (int k = 0; k < NTAPS; ++k) {
    tp[o * 20 + k] = (float)k * D;
    tp[o * 20 + 10 + k] = (float)pow((double)av, (double)k);
  }
}

// ---------------- fast body (interior tiles: all taps valid) ----------------
// Center-quantized const-frac: fract(fl(t-kD)) is constant in t within a
// binade (RNE of I+phi at grid 2^-e is I-independent), so fc computed at the
// tile center replicates the reference per-t value for the dominant binade;
// other-binade lanes differ by <= 2^-9*|dx| (continuity-bounded). Inner tap:
// v_add(idx) + ds_read2_b32 + 2 fma = ~4 VALU + 1 DS. k=0 (identity tap)
// hoisted into acc init; params preloaded per-oi as 5 float4 (one lgkm wait).
__device__ __forceinline__ void comb_body_fast(const float* __restrict__ tp,
                                               float* __restrict__ outp,
                                               const float* sx, int oc,
                                               int t0, int tid) {
  float tcf = (float)(t0 + TC);
  int cbase = PAD - t0 - TC;   // idx_j = i0c + cbase + tid + 256*j
  float xt[NT];
#pragma unroll
  for (int j = 0; j < NT; ++j) xt[j] = sx[PAD + tid + 256 * j];
#pragma unroll 1
  for (int oi = 0; oi < OCHUNK; ++oi) {
    const float4* p4 = (const float4*)(tp + (oc + oi) * 20);
    float4 q0 = p4[0], q1 = p4[1], q2 = p4[2], q3 = p4[3], q4 = p4[4];
    float kD[NTAPS] = {q0.x, q0.y, q0.z, q0.w, q1.x, q1.y, q1.z, q1.w, q2.x, q2.y};
    float ak[NTAPS] = {q2.z, q2.w, q3.x, q3.y, q3.z, q3.w, q4.x, q4.y, q4.z, q4.w};
    float acc[NT];
#pragma unroll
    for (int j = 0; j < NT; ++j) acc[j] = xt[j];   // k=0: a^0 * x[t]
#pragma unroll
    for (int k = 1; k < NTAPS; ++k) {
      float pc = tcf - kD[k];                  // reference pos at t_c (>0 here)
      float fc = __builtin_amdgcn_fractf(pc);  // frac_ref(t_c), exact
      int sb = (int)(pc - fc) + cbase + tid;   // pc-fc == floor(pc) exactly
      float w1 = ak[k] * fc;
      float w0 = ak[k] - w1;
#pragma unroll
      for (int j = 0; j < NT; ++j) {
        int idx = sb + 256 * j;
        float x0 = sx[idx];                    // adjacent -> ds_read2_b32
        float x1 = sx[idx + 1];
        acc[j] = fmaf(w0, x0, fmaf(w1, x1, acc[j]));
      }
    }
#pragma unroll
    for (int j = 0; j < NT; ++j)
      outp[(size_t)oi * T_LEN + 256 * j] = acc[j];
  }
}

// ---------------- exact body (edge tiles bx 0..2: per-t arithmetic + mask) ---
// Quantized-frac i0 flips at the i0==-1 mask boundary can produce O(1) errors,
// so edge tiles keep the bit-faithful per-element chain (12% of work).
__device__ __forceinline__ void comb_body_edge(const float* __restrict__ tp,
                                               float* __restrict__ outp,
                                               const float* sx, int oc,
                                               const float* tf, int base_g) {
#pragma unroll 1
  for (int oi = 0; oi < OCHUNK; ++oi) {
    const float4* p4 = (const float4*)(tp + (oc + oi) * 20);
    float4 q0 = p4[0], q1 = p4[1], q2 = p4[2], q3 = p4[3], q4 = p4[4];
    float kD[NTAPS] = {q0.x, q0.y, q0.z, q0.w, q1.x, q1.y, q1.z, q1.w, q2.x, q2.y};
    float ak[NTAPS] = {q2.z, q2.w, q3.x, q3.y, q3.z, q3.w, q4.x, q4.y, q4.z, q4.w};
    float acc[NT];
#pragma unroll
    for (int j = 0; j < NT; ++j) acc[j] = 0.0f;
#pragma unroll
    for (int k = 0; k < NTAPS; ++k) {
#pragma unroll
      for (int j = 0; j < NT; ++j) {
        float pos = tf[j] - kD[k];                  // fl(t - kD), exact chain
        float frac = __builtin_amdgcn_fractf(pos);
        int idx = (int)pos - base_g;                // trunc==floor for pos>=0;
        float x0 = sx[idx];                         // neg-pos taps masked below
        float x1 = sx[idx + 1];
        float tap = fmaf(frac, x1 - x0, x0);
        tap = (pos >= 0.0f) ? tap : 0.0f;           // valid = (floor(pos)>=0)
        acc[j] = fmaf(ak[k], tap, acc[j]);
      }
    }
#pragma unroll
    for (int j = 0; j < NT; ++j)
      outp[(size_t)oi * T_LEN + 256 * j] = acc[j];
  }
}

__global__ __launch_bounds__(256) void comb_main_kernel(
    const float* __restrict__ x, const float* __restrict__ tp,
    float* __restrict__ out) {
  __shared__ float sx[NSTAGE_AL];
  int bx = blockIdx.x;
  int t0 = bx * TILE_T;
  int b = blockIdx.y;
  int oc = blockIdx.z * OCHUNK;
  const float* __restrict__ xrow = x + b * T_LEN;
  int base_g = t0 - PAD;
  int tid = threadIdx.x;

  if (bx >= 3 && bx <= 23) {
    // interior: every g in [0, 31999] -> aligned float4 copy (base_g % 4 == 0)
    float4* s4 = (float4*)sx;
    const float4* g4 = (const float4*)(xrow + base_g);
#pragma unroll 1
    for (int j = tid; j < NSTAGE_AL / 4; j += 256) s4[j] = g4[j];
  } else {
    // edge tiles: g<0 -> 0.0 (invalid-tap reads are zero / masked);
    // g >= T-1 -> clamp to T-1 (replicates reference i1 clip, weight 0)
#pragma unroll 1
    for (int j = tid; j < NSTAGE_AL; j += 256) {
      int g = base_g + j;
      float v = 0.0f;
      if (g >= 0) v = xrow[g < T_LEN - 1 ? g : T_LEN - 1];
      sx[j] = v;
    }
  }
  __syncthreads();

  float* outp = out + ((size_t)b * O_N + oc) * T_LEN + t0 + tid;

  if (bx >= 3) {       // pos >= 960 for every tap: all valid, fast path
    comb_body_fast(tp, outp, sx, oc, t0, tid);
  } else {
    float tf[NT];
#pragma unroll
    for (int j = 0; j < NT; ++j) tf[j] = (float)(t0 + tid + 256 * j);
    comb_body_edge(tp, outp, sx, oc, tf, base_g);
  }
}

// ---------------- launch ----------------
extern "C" void kernel_launch(void* const* d_in, const int* in_sizes, int n_in,
                              void* d_out, int out_size, void* d_ws,
                              size_t ws_size, hipStream_t stream) {
  const float* x = (const float*)d_in[0];  // (8,1,32000) f32
  const float* f = (const float*)d_in[1];  // (128,1) f32
  const float* a = (const float*)d_in[2];  // (128,1) f32
  float* out = (float*)d_out;              // (8,128,32000) f32
  float* tp = (float*)d_ws;                // 128*20 floats = 10 KB scratch

  comb_params_kernel<<<1, 128, 0, stream>>>(f, a, tp);

  dim3 grid(T_LEN / TILE_T, B_N, O_N / OCHUNK);  // (25, 8, 16) = 3200 blocks
  comb_main_kernel<<<grid, 256, 0, stream>>>(x, tp, out);
}

// Round 8
// 169.515 us; speedup vs baseline: 1.1629x; 1.0263x over previous
//
#include <hip/hip_runtime.h>
#include <math.h>

#define T_LEN 32000
#define B_N 8
#define O_N 128
#define NTAPS 10
#define TILE_T 1280            // 5 CONSECUTIVE t per thread x 256 threads
#define PAD 2944               // >= ceil(9*Dmax)+margin, Dmax = 320; PAD % 4 == 0
#define NSTAGE (TILE_T + PAD + 1)        // 4225 pairs
#define NSTAGE_AL ((NSTAGE + 3) & ~3)    // 4228 pairs = 33.8 KB LDS
#define OCHUNK 8
#define TC 640                 // tile-center offset for const-frac quantization

// ---------------- kernel 1: per-channel tap parameters -> d_ws ----------------
// f = fl32(50 * 40^sigmoid(f_raw)), D = fl32(16000/f), kD = fl32(k*D), a^k.
// f64 for sigmoid/pow accuracy, one final rounding to f32.
__global__ __launch_bounds__(128) void comb_params_kernel(
    const float* __restrict__ f, const float* __restrict__ a,
    float* __restrict__ tp) {
  int o = threadIdx.x;  // 128 threads, 1 block
  double fr = (double)f[o];
  double sig = 1.0 / (1.0 + exp(-fr));
  float ff = (float)(50.0 * pow(40.0, sig));
  float D = 16000.0f / ff;
  float av = a[o];
  for (int k = 0; k < NTAPS; ++k) {
    tp[o * 20 + k] = (float)k * D;
    tp[o * 20 + 10 + k] = (float)pow((double)av, (double)k);
  }
}

#define LOAD_PARAMS                                                        \
  const float4* p4 = (const float4*)(tp + (oc + oi) * 20);                 \
  float4 q0 = p4[0], q1 = p4[1], q2 = p4[2], q3 = p4[3], q4 = p4[4];       \
  float kD[NTAPS] = {q0.x, q0.y, q0.z, q0.w, q1.x,                         \
                     q1.y, q1.z, q1.w, q2.x, q2.y};                        \
  float ak[NTAPS] = {q2.z, q2.w, q3.x, q3.y, q3.z,                         \
                     q3.w, q4.x, q4.y, q4.z, q4.w};

// ---------------- fast body (interior tiles: all taps valid) ----------------
// Const-frac (R7, verified absmax-neutral) + CONSECUTIVE-t lanes: one (o,k)
// tap for 5 consecutive outputs needs x[i..i+5] -> 3 aligned ds_read_b64 from
// the duplicated-pair LDS (immediate offsets 0/16/32) = 0.6 DS op per output
// vs 1.0 read2 before, at ~6 vs ~9 cyc each. Lane dword-stride 10 distributes
// exactly 4 accesses/bank = wave64-b64 structural minimum: conflict-free.
__device__ __forceinline__ void comb_body_fast(const float* __restrict__ tp,
                                               float* __restrict__ outp,
                                               const float2* sx2, int oc,
                                               int t0, int tid) {
  float tcf = (float)(t0 + TC);
  int cbase = PAD - t0 - TC + 5 * tid;
  // k=0 (identity tap): pairs at PAD + 5*tid, reused across all oi
  int b0 = PAD + 5 * tid;
  float2 A0 = sx2[b0], B0 = sx2[b0 + 2], C0 = sx2[b0 + 4];
#pragma unroll 1
  for (int oi = 0; oi < OCHUNK; ++oi) {
    LOAD_PARAMS
    float acc[5] = {A0.x, A0.y, B0.x, B0.y, C0.x};  // a^0 * x[t]
#pragma unroll
    for (int k = 1; k < NTAPS; ++k) {
      float pc = tcf - kD[k];                  // reference pos at t_c (>0 here)
      float fc = __builtin_amdgcn_fractf(pc);  // frac_ref(t_c), exact
      int sb = (int)(pc - fc) + cbase;         // pc-fc == floor(pc) exactly
      float w1 = ak[k] * fc;
      float w0 = ak[k] - w1;
      float2 A = sx2[sb];                      // x[i], x[i+1]
      float2 B = sx2[sb + 2];                  // x[i+2], x[i+3]
      float2 C = sx2[sb + 4];                  // x[i+4], x[i+5]
      acc[0] = fmaf(w0, A.x, fmaf(w1, A.y, acc[0]));
      acc[1] = fmaf(w0, A.y, fmaf(w1, B.x, acc[1]));
      acc[2] = fmaf(w0, B.x, fmaf(w1, B.y, acc[2]));
      acc[3] = fmaf(w0, B.y, fmaf(w1, C.x, acc[3]));
      acc[4] = fmaf(w0, C.x, fmaf(w1, C.y, acc[4]));
    }
#pragma unroll
    for (int u = 0; u < 5; ++u) outp[(size_t)oi * T_LEN + u] = acc[u];
  }
}

// ---------------- exact body (edge tiles bx 0..2: per-t arithmetic + mask) ---
// Quantized-frac i0 flips at the i0==-1 mask boundary can produce O(1) errors,
// so edge tiles keep the bit-faithful per-element chain (12% of work).
__device__ __forceinline__ void comb_body_edge(const float* __restrict__ tp,
                                               float* __restrict__ outp,
                                               const float2* sx2, int oc,
                                               int t0, int tid, int base_g) {
  float tf[5];
#pragma unroll
  for (int u = 0; u < 5; ++u) tf[u] = (float)(t0 + 5 * tid + u);
#pragma unroll 1
  for (int oi = 0; oi < OCHUNK; ++oi) {
    LOAD_PARAMS
    float acc[5];
#pragma unroll
    for (int u = 0; u < 5; ++u) acc[u] = 0.0f;
#pragma unroll
    for (int k = 0; k < NTAPS; ++k) {
#pragma unroll
      for (int u = 0; u < 5; ++u) {
        float pos = tf[u] - kD[k];                  // fl(t - kD), exact chain
        float frac = __builtin_amdgcn_fractf(pos);
        int idx = (int)pos - base_g;                // trunc==floor for pos>=0;
        float2 xv = sx2[idx];                       // neg-pos taps masked below
        float tap = fmaf(frac, xv.y - xv.x, xv.x);
        tap = (pos >= 0.0f) ? tap : 0.0f;           // valid = (floor(pos)>=0)
        acc[u] = fmaf(ak[k], tap, acc[u]);
      }
    }
#pragma unroll
    for (int u = 0; u < 5; ++u) outp[(size_t)oi * T_LEN + u] = acc[u];
  }
}

__global__ __launch_bounds__(256) void comb_main_kernel(
    const float* __restrict__ x, const float* __restrict__ tp,
    float* __restrict__ out) {
  __shared__ float2 sx2[NSTAGE_AL];
  int bx = blockIdx.x;
  int t0 = bx * TILE_T;
  int b = blockIdx.y;
  int oc = blockIdx.z * OCHUNK;
  const float* __restrict__ xrow = x + b * T_LEN;
  int base_g = t0 - PAD;
  int tid = threadIdx.x;

  if (bx >= 3 && bx <= 23) {
    // interior: g in [0, 31999] everywhere -> float4 load (base_g % 4 == 0),
    // write 4 overlapped pairs; 'nx' bridges to the next quad.
    const float4* g4 = (const float4*)(xrow + base_g);
#pragma unroll 1
    for (int j = tid; j < NSTAGE_AL / 4; j += 256) {
      float4 v = g4[j];
      float nx = xrow[base_g + 4 * j + 4];
      sx2[4 * j + 0] = make_float2(v.x, v.y);
      sx2[4 * j + 1] = make_float2(v.y, v.z);
      sx2[4 * j + 2] = make_float2(v.z, v.w);
      sx2[4 * j + 3] = make_float2(v.w, nx);
    }
  } else {
    // edge tiles: g<0 -> 0.0 (invalid-tap reads are zero / masked);
    // g >= T-1 -> clamp to T-1 (replicates reference i1 clip, weight 0)
#pragma unroll 1
    for (int j = tid; j < NSTAGE_AL; j += 256) {
      int g = base_g + j;
      float v0 = 0.0f, v1 = 0.0f;
      if (g >= 0) v0 = xrow[g < T_LEN - 1 ? g : T_LEN - 1];
      if (g + 1 >= 0) v1 = xrow[g + 1 < T_LEN - 1 ? g + 1 : T_LEN - 1];
      sx2[j] = make_float2(v0, v1);
    }
  }
  __syncthreads();

  float* outp = out + ((size_t)b * O_N + oc) * T_LEN + t0 + 5 * tid;

  if (bx >= 3) {       // pos >= 960 for every tap: all valid, fast path
    comb_body_fast(tp, outp, sx2, oc, t0, tid);
  } else {
    comb_body_edge(tp, outp, sx2, oc, t0, tid, base_g);
  }
}

// ---------------- launch ----------------
extern "C" void kernel_launch(void* const* d_in, const int* in_sizes, int n_in,
                              void* d_out, int out_size, void* d_ws,
                              size_t ws_size, hipStream_t stream) {
  const float* x = (const float*)d_in[0];  // (8,1,32000) f32
  const float* f = (const float*)d_in[1];  // (128,1) f32
  const float* a = (const float*)d_in[2];  // (128,1) f32
  float* out = (float*)d_out;              // (8,128,32000) f32
  float* tp = (float*)d_ws;                // 128*20 floats = 10 KB scratch

  comb_params_kernel<<<1, 128, 0, stream>>>(f, a, tp);

  dim3 grid(T_LEN / TILE_T, B_N, O_N / OCHUNK);  // (25, 8, 16) = 3200 blocks
  comb_main_kernel<<<grid, 256, 0, stream>>>(x, tp, out);
}